// Round 4
// baseline (344.154 us; speedup 1.0000x reference)
//
#include <hip/hip_runtime.h>
#include <hip/hip_bf16.h>

#define B_ 64
#define N_ 2048
#define I_ 16
#define J_ 32
#define O_ 32
#define JO_ 1024
#define SPLITS 32
#define ASF_NSET 8
#define ASF_BLOCKS (N_ / ASF_NSET)   // 256

typedef __attribute__((ext_vector_type(8))) short bf16x8;
typedef __attribute__((ext_vector_type(16))) float f32x16;
typedef unsigned short u16;
typedef unsigned int u32;

__device__ __forceinline__ float bf2f(u16 u) {
  union { u32 i; float f; } c; c.i = ((u32)u) << 16; return c.f;
}
__device__ __forceinline__ u16 f2bf(float f) {
  union { float f; u32 i; } c; c.f = f;
  u32 r = (c.i + 0x7fffu + ((c.i >> 16) & 1u)) >> 16;
  return (u16)r;
}
// one-instruction pack of 2 f32 -> 2 bf16 (RNE)
__device__ __forceinline__ u32 pack2_pk(float lo, float hi) {
  u32 r;
  asm("v_cvt_pk_bf16_f32 %0, %1, %2" : "=v"(r) : "v"(lo), "v"(hi));
  return r;
}
// scale packed bf16 pair by cv
__device__ __forceinline__ u32 scale2_pk(u32 p, float cv) {
  union { u32 i; float f; } lo, hi;
  lo.i = p << 16; hi.i = p & 0xffff0000u;
  return pack2_pk(lo.f * cv, hi.f * cv);
}

// ---------------------------------------------------------------------------
// xconv: x f32 [b][n][i] -> xt bf16 [n][b][i]
// ---------------------------------------------------------------------------
__global__ __launch_bounds__(256) void xconv_kernel(
    const float* __restrict__ xf, u16* __restrict__ xt)
{
  const int idx = blockIdx.x * 256 + threadIdx.x;   // = b*2048 + n
  const int b = idx >> 11, n = idx & 2047;
  const float4* sp = (const float4*)(xf + (size_t)idx * 16);
  float4 f0 = sp[0], f1 = sp[1], f2 = sp[2], f3 = sp[3];
  uint4 d0, d1;
  d0.x = pack2_pk(f0.x, f0.y); d0.y = pack2_pk(f0.z, f0.w);
  d0.z = pack2_pk(f1.x, f1.y); d0.w = pack2_pk(f1.z, f1.w);
  d1.x = pack2_pk(f2.x, f2.y); d1.y = pack2_pk(f2.z, f2.w);
  d1.z = pack2_pk(f3.x, f3.y); d1.w = pack2_pk(f3.z, f3.w);
  uint4* dp = (uint4*)(xt + ((size_t)n * 64 + b) * 16);
  dp[0] = d0; dp[1] = d1;
}

// ---------------------------------------------------------------------------
// WSF kernel: fused wconv + sf iter-0 (uniform c). Reads w f32 once, writes
// wb bf16, accumulates iter-0 s partials (32 splits, no atomics).
// ---------------------------------------------------------------------------
#define SF_NPW 16

__global__ __launch_bounds__(256, 4) void wsf_kernel(
    const float* __restrict__ wf, u16* __restrict__ wb,
    const u16* __restrict__ xt, float* __restrict__ s_part)
{
  __shared__ float red[4][2048];   // 32 KB
  const int tid = threadIdx.x;
  const int wave = tid >> 6, lane = tid & 63;
  const int l31 = lane & 31, h = lane >> 5;
  const int j = blockIdx.x, split = blockIdx.y;
  const int n0 = (split * 4 + wave) * SF_NPW;
  f32x16 acc0 = {0.f, 0.f, 0.f, 0.f, 0.f, 0.f, 0.f, 0.f,
                 0.f, 0.f, 0.f, 0.f, 0.f, 0.f, 0.f, 0.f};
  f32x16 acc1 = acc0;

  #pragma unroll 4
  for (int i = 0; i < SF_NPW; ++i) {
    const int n = n0 + i;
    const size_t row = (size_t)n * JO_ + j * 32 + l31;
    const float* wsrc = wf + row * 16 + h * 8;
    const float4 f0 = *(const float4*)(wsrc);
    const float4 f1 = *(const float4*)(wsrc + 4);
    union { uint4 u4; bf16x8 bv; } wd;
    wd.u4.x = pack2_pk(f0.x, f0.y); wd.u4.y = pack2_pk(f0.z, f0.w);
    wd.u4.z = pack2_pk(f1.x, f1.y); wd.u4.w = pack2_pk(f1.z, f1.w);
    *(uint4*)(wb + row * 16 + h * 8) = wd.u4;   // persist for asf passes
    const bf16x8 x0 = *(const bf16x8*)(xt + ((size_t)n * 64 + l31) * 16 + h * 8);
    const bf16x8 x1 = *(const bf16x8*)(xt + ((size_t)n * 64 + 32 + l31) * 16 + h * 8);
    acc0 = __builtin_amdgcn_mfma_f32_32x32x16_bf16(wd.bv, x0, acc0, 0, 0, 0);
    acc1 = __builtin_amdgcn_mfma_f32_32x32x16_bf16(wd.bv, x1, acc1, 0, 0, 0);
  }
  #pragma unroll
  for (int r = 0; r < 16; ++r) {
    const int o = (r & 3) + 8 * (r >> 2) + 4 * h;
    red[wave][o * 64 + l31] = acc0[r];
    red[wave][o * 64 + 32 + l31] = acc1[r];
  }
  __syncthreads();
  float* dst = s_part + (size_t)split * (JO_ * B_) + (size_t)j * 32 * 64;
  #pragma unroll
  for (int k = 0; k < 8; ++k) {
    const int idx = tid + 256 * k;
    dst[idx] = red[0][idx] + red[1][idx] + red[2][idx] + red[3][idx];
  }
}

// ---------------------------------------------------------------------------
// ASF kernel: fused agreement + softmax + scaled-accumulate (one wb pass).
// Block = 8 n (full j coverage -> in-block softmax), 512 thr = 8 waves x 4
// j-tiles. Phase1: pred MFMA -> dot v4 -> logits to LDS [nn][t][b] (64KB,
// conflict-free). Softmax: 512 thr = 8n x 64b, c stays f32 in LDS. Phase2:
// reload wfr (L3: block slice 256KB), scale x by c, MFMA into persistent
// acc (128 VGPR, static idx), write per-block f32 partial (no ct buffer).
// ---------------------------------------------------------------------------
__global__ __launch_bounds__(512, 2) void asf_kernel(
    const u16* __restrict__ xt, const u16* __restrict__ wb,
    const u16* __restrict__ v4, float* __restrict__ s_part)
{
  __shared__ float lgs[ASF_NSET][32][64];   // [nn][t][b] = 64 KB exactly
  const int tid = threadIdx.x;
  const int wave = tid >> 6, lane = tid & 63;
  const int l31 = lane & 31, h = lane >> 5;
  const int nbase = blockIdx.x * ASF_NSET;
  const f32x16 zero16 = {0.f, 0.f, 0.f, 0.f, 0.f, 0.f, 0.f, 0.f,
                         0.f, 0.f, 0.f, 0.f, 0.f, 0.f, 0.f, 0.f};

  // ---- phase 1: logits ----
  for (int nn = 0; nn < ASF_NSET; ++nn) {
    const int n = nbase + nn;
    const bf16x8 x0 = *(const bf16x8*)(xt + ((size_t)n * 64 + l31) * 16 + h * 8);
    const bf16x8 x1 = *(const bf16x8*)(xt + ((size_t)n * 64 + 32 + l31) * 16 + h * 8);
    #pragma unroll 2
    for (int q = 0; q < 4; ++q) {
      const int t = wave * 4 + q;
      const bf16x8 wfr =
          *(const bf16x8*)(wb + ((size_t)n * JO_ + t * 32 + l31) * 16 + h * 8);
      f32x16 p0 = __builtin_amdgcn_mfma_f32_32x32x16_bf16(wfr, x0, zero16, 0, 0, 0);
      f32x16 p1 = __builtin_amdgcn_mfma_f32_32x32x16_bf16(wfr, x1, zero16, 0, 0, 0);
      float s0 = 0.f, s1 = 0.f;
      #pragma unroll
      for (int g = 0; g < 4; ++g) {
        const int vbase = (((t * 4 + g) * 2 + h) * 64) * 4;  // u16 units
        const ushort4 va = *(const ushort4*)(v4 + vbase + l31 * 4);
        const ushort4 vb = *(const ushort4*)(v4 + vbase + (32 + l31) * 4);
        s0 += p0[g * 4 + 0] * bf2f(va.x) + p0[g * 4 + 1] * bf2f(va.y)
            + p0[g * 4 + 2] * bf2f(va.z) + p0[g * 4 + 3] * bf2f(va.w);
        s1 += p1[g * 4 + 0] * bf2f(vb.x) + p1[g * 4 + 1] * bf2f(vb.y)
            + p1[g * 4 + 2] * bf2f(vb.z) + p1[g * 4 + 3] * bf2f(vb.w);
      }
      s0 += __shfl_xor(s0, 32, 64);   // combine h-halves (same col b)
      s1 += __shfl_xor(s1, 32, 64);
      // h=0 lane l31 owns b=l31 (s0); h=1 lane owns b=32+l31 (s1)
      lgs[nn][t][lane] = h ? s1 : s0;
    }
  }
  __syncthreads();

  // ---- softmax: one (n,b) per thread, c written back in place (f32) ----
  {
    const int n2 = tid >> 6, b = tid & 63;
    float lv[32];
    float mx = -1e30f;
    #pragma unroll
    for (int t = 0; t < 32; ++t) { lv[t] = lgs[n2][t][b]; mx = fmaxf(mx, lv[t]); }
    float sm = 0.f;
    #pragma unroll
    for (int t = 0; t < 32; ++t) { lv[t] = __expf(lv[t] - mx); sm += lv[t]; }
    const float inv = 1.f / sm;
    #pragma unroll
    for (int t = 0; t < 32; ++t) lgs[n2][t][b] = lv[t] * inv;
  }
  __syncthreads();

  // ---- phase 2: scaled accumulate (wfr reload hits L3; c from LDS) ----
  f32x16 a0_0 = zero16, a0_1 = zero16, a0_2 = zero16, a0_3 = zero16;
  f32x16 a1_0 = zero16, a1_1 = zero16, a1_2 = zero16, a1_3 = zero16;
  for (int nn = 0; nn < ASF_NSET; ++nn) {
    const int n = nbase + nn;
    union { bf16x8 v; u32 u[4]; } xa, xb;
    xa.v = *(const bf16x8*)(xt + ((size_t)n * 64 + l31) * 16 + h * 8);
    xb.v = *(const bf16x8*)(xt + ((size_t)n * 64 + 32 + l31) * 16 + h * 8);
    #pragma unroll
    for (int q = 0; q < 4; ++q) {
      const int t = wave * 4 + q;
      const bf16x8 wfr =
          *(const bf16x8*)(wb + ((size_t)n * JO_ + t * 32 + l31) * 16 + h * 8);
      const float cv0 = lgs[nn][t][l31];        // broadcast across h
      const float cv1 = lgs[nn][t][32 + l31];
      union { bf16x8 v; u32 u[4]; } s0, s1;
      s0.u[0] = scale2_pk(xa.u[0], cv0); s0.u[1] = scale2_pk(xa.u[1], cv0);
      s0.u[2] = scale2_pk(xa.u[2], cv0); s0.u[3] = scale2_pk(xa.u[3], cv0);
      s1.u[0] = scale2_pk(xb.u[0], cv1); s1.u[1] = scale2_pk(xb.u[1], cv1);
      s1.u[2] = scale2_pk(xb.u[2], cv1); s1.u[3] = scale2_pk(xb.u[3], cv1);
      if (q == 0) {
        a0_0 = __builtin_amdgcn_mfma_f32_32x32x16_bf16(wfr, s0.v, a0_0, 0, 0, 0);
        a1_0 = __builtin_amdgcn_mfma_f32_32x32x16_bf16(wfr, s1.v, a1_0, 0, 0, 0);
      } else if (q == 1) {
        a0_1 = __builtin_amdgcn_mfma_f32_32x32x16_bf16(wfr, s0.v, a0_1, 0, 0, 0);
        a1_1 = __builtin_amdgcn_mfma_f32_32x32x16_bf16(wfr, s1.v, a1_1, 0, 0, 0);
      } else if (q == 2) {
        a0_2 = __builtin_amdgcn_mfma_f32_32x32x16_bf16(wfr, s0.v, a0_2, 0, 0, 0);
        a1_2 = __builtin_amdgcn_mfma_f32_32x32x16_bf16(wfr, s1.v, a1_2, 0, 0, 0);
      } else {
        a0_3 = __builtin_amdgcn_mfma_f32_32x32x16_bf16(wfr, s0.v, a0_3, 0, 0, 0);
        a1_3 = __builtin_amdgcn_mfma_f32_32x32x16_bf16(wfr, s1.v, a1_3, 0, 0, 0);
      }
    }
  }
  // ---- store per-block partial: full [jo][b] coverage, each slot once ----
  float* dst = s_part + (size_t)blockIdx.x * (JO_ * B_);
  #pragma unroll
  for (int q = 0; q < 4; ++q) {
    const int t = wave * 4 + q;
    const f32x16 a0 = (q == 0) ? a0_0 : (q == 1) ? a0_1 : (q == 2) ? a0_2 : a0_3;
    const f32x16 a1 = (q == 0) ? a1_0 : (q == 1) ? a1_1 : (q == 2) ? a1_2 : a1_3;
    #pragma unroll
    for (int r = 0; r < 16; ++r) {
      const int o = (r & 3) + 8 * (r >> 2) + 4 * h;
      dst[(size_t)(t * 32 + o) * 64 + l31] = a0[r];
      dst[(size_t)(t * 32 + o) * 64 + 32 + l31] = a1[r];
    }
  }
}

// ---------------------------------------------------------------------------
// RS kernel: column-sum of nsplit partial buffers -> s_red (coalesced).
// grid 256, block 256 (64K outputs).
// ---------------------------------------------------------------------------
__global__ __launch_bounds__(256) void rs_kernel(
    const float* __restrict__ src, float* __restrict__ dst, int nsplit)
{
  const int idx = blockIdx.x * 256 + threadIdx.x;
  float s = 0.f;
  #pragma unroll 8
  for (int p = 0; p < nsplit; ++p) s += src[(size_t)p * (JO_ * B_) + idx];
  dst[idx] = s;
}

// ---------------------------------------------------------------------------
// R kernel: squash over o from s_red[jo][b] (256KB, L2/L3-resident).
// mode 0: v f32 + v4; 1: v4=f2bf(v+vprev); 2: out.
// grid 1024 (= 64 b x 16 jgroups), block 64 (2 j x 32 o).
// ---------------------------------------------------------------------------
__global__ __launch_bounds__(64) void r_kernel(
    const float* __restrict__ s_red, float* __restrict__ v,
    const float* __restrict__ vprev, u16* __restrict__ v4,
    float* __restrict__ out, int mode, float scale)
{
  const int tid = threadIdx.x;
  const int jj = tid >> 5, o = tid & 31;
  const int b = blockIdx.x >> 4, jg = blockIdx.x & 15;
  const int j = jg * 2 + jj;
  const float s = s_red[(size_t)(j * 32 + o) * 64 + b] * scale;
  float sq = s * s;
  #pragma unroll
  for (int m = 16; m >= 1; m >>= 1) sq += __shfl_xor(sq, m, 64);
  const float sc = sq / (1.f + sq) * rsqrtf(sq + 1e-8f);
  const float vv = sc * s;
  const size_t off = (size_t)b * JO_ + j * 32 + o;
  const int g = o >> 3, hh = (o >> 2) & 1, rr = o & 3;
  const size_t v4off = ((((size_t)j * 4 + g) * 2 + hh) * 64 + b) * 4 + rr;
  if (mode == 0) { v[off] = vv; v4[v4off] = f2bf(vv); }
  else if (mode == 1) { v4[v4off] = f2bf(vv + vprev[off]); }
  else { out[off] = vv; }
}

// ---------------------------------------------------------------------------
extern "C" void kernel_launch(void* const* d_in, const int* in_sizes, int n_in,
                              void* d_out, int out_size, void* d_ws, size_t ws_size,
                              hipStream_t stream) {
  const float* x = (const float*)d_in[0];
  const float* w = (const float*)d_in[1];
  float* out = (float*)d_out;
  char* ws = (char*)d_ws;
  // layout: wb 64MB | xt 4MB | s_part32 8MB | s_red 256K | v0 256K | v4 128K
  //         | s_part256 64MB @ 80MB  (total 144MB; ws is 512MB per fills)
  u16*   wb       = (u16*)ws;
  u16*   xt       = (u16*)(ws + (size_t)64 * 1024 * 1024);
  float* s_part32 = (float*)(ws + (size_t)68 * 1024 * 1024);
  float* s_red    = (float*)(ws + (size_t)76 * 1024 * 1024);
  float* v0       = (float*)(ws + (size_t)76 * 1024 * 1024 + 262144);
  u16*   v4       = (u16*)(ws + (size_t)76 * 1024 * 1024 + 2 * 262144);
  float* s_partA  = (float*)(ws + (size_t)80 * 1024 * 1024);

  dim3 sfg(32, SPLITS), sfb(256);
  dim3 ag(ASF_BLOCKS), ab(512);
  dim3 rsg(256), rsb(256);
  dim3 rg(1024), rb(64);

  xconv_kernel<<<dim3(512), dim3(256), 0, stream>>>(x, xt);
  // iter 0: fused wconv + uniform-c accumulate (c folded as 1/32 in r)
  wsf_kernel<<<sfg, sfb, 0, stream>>>(w, wb, xt, s_part32);
  rs_kernel<<<rsg, rsb, 0, stream>>>(s_part32, s_red, SPLITS);
  r_kernel<<<rg, rb, 0, stream>>>(s_red, v0, v0, v4, out, 0, 0.03125f);
  // iter 1: fused agreement+softmax+scaled-accumulate
  asf_kernel<<<ag, ab, 0, stream>>>(xt, wb, v4, s_partA);
  rs_kernel<<<rsg, rsb, 0, stream>>>(s_partA, s_red, ASF_BLOCKS);
  r_kernel<<<rg, rb, 0, stream>>>(s_red, v0, v0, v4, out, 1, 1.0f);
  // iter 2 (logits = pred . (v0+v1) via v4)
  asf_kernel<<<ag, ab, 0, stream>>>(xt, wb, v4, s_partA);
  rs_kernel<<<rsg, rsb, 0, stream>>>(s_partA, s_red, ASF_BLOCKS);
  r_kernel<<<rg, rb, 0, stream>>>(s_red, v0, v0, v4, out, 2, 1.0f);
}